// Round 5
// baseline (573.207 us; speedup 1.0000x reference)
//
#include <hip/hip_runtime.h>
#include <stdint.h>

typedef __bf16 bf16x8 __attribute__((ext_vector_type(8)));
typedef float  f32x4  __attribute__((ext_vector_type(4)));

#define BLD   16777216   // 4096*16*256
#define DDIM  256
#define NT    16         // tiles per block (2048 tiles per encoder / 128 blocks)

// ---- LDS map (bytes) ----
// A double-buffer: buf{0,1} x {G,P} x (32 rows x 256 cols bf16, XOR-swizzled) = 64KB
#define ABUF_OFF  0
#define PARAM_OFF 65536    // 8 arrays x 256 f32 = 8KB
#define STATS_OFF 73728    // 32 rows x 144B (4wq x 2mat x 16B + 16B pad) = 4608B
#define ROWC_OFF  78336    // 32 rows x 9 f32 = 1152B
#define CONST_OFF 79488    // 4 f32
#define EXG_OFF   79504    // contrib_g rows 16..31: 16 x 260 f32 (padded) = 16640B
#define EXP_OFF   96144    // contrib_p rows 0..15:  16 x 260 f32 = 16640B
#define SMEM_BYTES 112784  // 1 block/CU

__device__ __forceinline__ float sigmoid_fast(float x){
  float e = __builtin_amdgcn_exp2f(-1.44269504f * x);
  return __builtin_amdgcn_rcpf(1.0f + e);
}

__device__ __forceinline__ bf16x8 pack8(float4 a, float4 b){
  bf16x8 r;
  r[0]=(__bf16)a.x; r[1]=(__bf16)a.y; r[2]=(__bf16)a.z; r[3]=(__bf16)a.w;
  r[4]=(__bf16)b.x; r[5]=(__bf16)b.y; r[6]=(__bf16)b.z; r[7]=(__bf16)b.w;
  return r;
}
__device__ __forceinline__ bf16x8 cvt8(const float* p){
  return pack8(*(const float4*)p, *(const float4*)(p+4));
}

// param array ids: 0 bg, 1 gng, 2 gnb, 3 bp, 4 png, 5 pnb, 6 wga, 7 wpa
__device__ __forceinline__ float ldp(const unsigned char* sm, int arr, int col){
  return ((const float*)(sm + PARAM_OFF))[arr*256 + col];
}

__global__ __launch_bounds__(512, 2)
void kd_kernel(const float* __restrict__ gfeat, const float* __restrict__ pfeat,
               const float* __restrict__ Wg,  const float* __restrict__ bg,
               const float* __restrict__ gng, const float* __restrict__ gnb,
               const float* __restrict__ Wp,  const float* __restrict__ bp,
               const float* __restrict__ pngm,const float* __restrict__ pnb,
               const float* __restrict__ wga, const float* __restrict__ bga,
               const float* __restrict__ wpa, const float* __restrict__ bpa,
               float* __restrict__ out)
{
  __shared__ __align__(16) unsigned char sm[SMEM_BYTES];
  const int tid  = threadIdx.x;        // 0..511
  const int n    = tid & 15;           // MFMA m/n lane
  const int q    = (tid >> 4) & 3;     // k-quad / row-quad
  const int w    = tid >> 6;           // wave 0..7
  const int mat  = w >> 2;             // 0: g-GEMM (Wg), 1: p-GEMM (Wp)
  const int wq   = w & 3;              // column group: cols [64*wq, 64*wq+64)
  const int e    = blockIdx.x & 1;     // encoder; pair blocks share feature reads (L3)
  const int b2   = blockIdx.x >> 1;    // 0..127

  const int q16  = q*16;
  const int xorv = (n & 7) << 4;       // A-LDS swizzle
  const int colb = wq*64 + n*4;

  // Reference swap: g-GEMM A-input is pfeat, p-GEMM A-input is gfeat.
  const float* srcG = pfeat;
  const float* srcP = gfeat;

  // ---- stage params (f32) into LDS
  if (tid < 256){
    float* pp = (float*)(sm + PARAM_OFF);
    pp[0*256 + tid] = bg  [e*256 + tid];
    pp[1*256 + tid] = gng [e*256 + tid];
    pp[2*256 + tid] = gnb [e*256 + tid];
    pp[3*256 + tid] = bp  [e*256 + tid];
    pp[4*256 + tid] = pngm[e*256 + tid];
    pp[5*256 + tid] = pnb [e*256 + tid];
    pp[6*256 + tid] = wga [e*256 + tid];
    pp[7*256 + tid] = wpa [e*256 + tid];
  }

  // per-thread staging geometry: 16 f32 per mat per tile (coalesced 64B/thread)
  const int sofs = tid*16;
  const int srow = sofs >> 8, scol = sofs & 255;
  const int sb0  = srow*512 + (( scol    *2) ^ ((srow & 7) << 4));
  const int sb1  = srow*512 + (((scol+8) *2) ^ ((srow & 7) << 4));

  // ---- stage tile 0 into buf0
  {
    const float* g0 = srcG + (size_t)(b2*NT)*8192 + sofs;
    const float* p0 = srcP + (size_t)(b2*NT)*8192 + sofs;
    float4 a0=*(const float4*)(g0), a1=*(const float4*)(g0+4), a2=*(const float4*)(g0+8), a3=*(const float4*)(g0+12);
    float4 c0=*(const float4*)(p0), c1=*(const float4*)(p0+4), c2=*(const float4*)(p0+8), c3=*(const float4*)(p0+12);
    *(bf16x8*)(sm + sb0)         = pack8(a0,a1);
    *(bf16x8*)(sm + sb1)         = pack8(a2,a3);
    *(bf16x8*)(sm + 16384 + sb0) = pack8(c0,c1);
    *(bf16x8*)(sm + 16384 + sb1) = pack8(c2,c3);
  }
  __syncthreads();   // params + A(tile0) staged

  // ---- dot-fold constants (wave 0): C0=sum(gng*wpa), C1=sum(gnb*wpa),
  //                                   C2=sum(png*wga), C3=sum(pnb*wga)
  if (tid < 64){
    float c0=0.f, c1=0.f, c2=0.f, c3=0.f;
    #pragma unroll
    for (int j = 0; j < 4; ++j){
      int c = tid*4 + j;
      float gng_ = ldp(sm,1,c), gnb_ = ldp(sm,2,c);
      float png_ = ldp(sm,4,c), pnb_ = ldp(sm,5,c);
      float wga_ = ldp(sm,6,c), wpa_ = ldp(sm,7,c);
      c0 += gng_*wpa_; c1 += gnb_*wpa_; c2 += png_*wga_; c3 += pnb_*wga_;
    }
    #pragma unroll
    for (int m = 1; m <= 32; m <<= 1){
      c0 += __shfl_xor(c0,m); c1 += __shfl_xor(c1,m);
      c2 += __shfl_xor(c2,m); c3 += __shfl_xor(c3,m);
    }
    if (tid == 0){
      float* cp = (float*)(sm + CONST_OFF);
      cp[0]=c0; cp[1]=c1; cp[2]=c2; cp[3]=c3;
    }
  }

  // ---- load this wave's W fragments ONCE into registers (128 VGPR).
  // frag(kk,t) = W[colb+t][kk*32 + q*8 .. +8]  (same values/order as prev rounds)
  const float* wsrc = (mat ? Wp : Wg) + (size_t)e*65536;
  bf16x8 wf[8][4];
  #pragma unroll
  for (int kk = 0; kk < 8; ++kk)
    #pragma unroll
    for (int t = 0; t < 4; ++t)
      wf[kk][t] = cvt8(wsrc + (size_t)(colb + t)*DDIM + kk*32 + q*8);

  // ---- persistent per-wave params (this mat only)
  const float* pp = (const float*)(sm + PARAM_OFF);
  float4 biasv = *(const float4*)(pp + (mat?3:0)*256 + colb);
  float4 gamv  = *(const float4*)(pp + (mat?4:1)*256 + colb);
  float4 betv  = *(const float4*)(pp + (mat?5:2)*256 + colb);
  float4 wav   = *(const float4*)(pp + (mat?6:7)*256 + colb);  // g: wpa, p: wga
  float wk[4];
  wk[0]=((float*)&gamv)[0]*((float*)&wav)[0]; wk[1]=((float*)&gamv)[1]*((float*)&wav)[1];
  wk[2]=((float*)&gamv)[2]*((float*)&wav)[2]; wk[3]=((float*)&gamv)[3]*((float*)&wav)[3];
  const float attb = mat ? bpa[e] : bga[e];

  int cur = 0;
  float4 pfG[4], pfP[4];

  for (int i = 0; i < NT; ++i){
    const int tile = b2*NT + i;

    // ---- acc init = linear bias (same fold as before)
    f32x4 acc[2][4];
    #pragma unroll
    for (int t = 0; t < 4; ++t){
      float bv = ((const float*)&biasv)[t];
      acc[0][t] = (f32x4){bv,bv,bv,bv};
      acc[1][t] = (f32x4){bv,bv,bv,bv};
    }

    // ---- K-loop: pure LDS + MFMA (W is in registers)
    {
      const unsigned char* slab = sm + cur*32768 + mat*16384;
      #pragma unroll
      for (int kk = 0; kk < 8; ++kk){
        int co = (kk*64 + q16) ^ xorv;
        bf16x8 a0 = *(const bf16x8*)(slab + (n     )*512 + co);
        bf16x8 a1 = *(const bf16x8*)(slab + (16 + n)*512 + co);
        #pragma unroll
        for (int t = 0; t < 4; ++t){
          acc[0][t] = __builtin_amdgcn_mfma_f32_16x16x32_bf16(a0, wf[kk][t], acc[0][t], 0,0,0);
          acc[1][t] = __builtin_amdgcn_mfma_f32_16x16x32_bf16(a1, wf[kk][t], acc[1][t], 0,0,0);
        }
      }
    }

    // ---- issue next tile's A loads (hidden under stats phase)
    if (i+1 < NT){
      const float* gN = srcG + (size_t)(tile+1)*8192 + sofs;
      const float* pN = srcP + (size_t)(tile+1)*8192 + sofs;
      #pragma unroll
      for (int v = 0; v < 4; ++v){
        pfG[v] = *(const float4*)(gN + v*4);
        pfP[v] = *(const float4*)(pN + v*4);
      }
    }

    // ---- stats (this mat): xs, xq (sum sq), xw (= sum x*gamma*att_w)
    #pragma unroll
    for (int s = 0; s < 2; ++s){
      #pragma unroll
      for (int reg = 0; reg < 4; ++reg){
        float xs=0.f, xq=0.f, xw=0.f;
        #pragma unroll
        for (int t = 0; t < 4; ++t){
          float x = acc[s][t][reg];
          xs += x; xq = fmaf(x,x,xq); xw = fmaf(x,wk[t],xw);
        }
        #pragma unroll
        for (int m = 1; m <= 8; m <<= 1){
          xs += __shfl_xor(xs,m); xq += __shfl_xor(xq,m); xw += __shfl_xor(xw,m);
        }
        if (n == 0){
          int r = s*16 + q*4 + reg;
          float4 st = {xs, xq, xw, 0.f};
          *(float4*)(sm + STATS_OFF + r*144 + (wq*2 + mat)*16) = st;
        }
      }
    }
    __syncthreads();   // (2) stats visible; prev-buf reads long done

    // ---- write prefetched A into buf^1 (overlaps rowc on wave 0)
    if (i+1 < NT){
      unsigned char* dst = sm + (cur^1)*32768;
      *(bf16x8*)(dst + sb0)         = pack8(pfG[0],pfG[1]);
      *(bf16x8*)(dst + sb1)         = pack8(pfG[2],pfG[3]);
      *(bf16x8*)(dst + 16384 + sb0) = pack8(pfP[0],pfP[1]);
      *(bf16x8*)(dst + 16384 + sb1) = pack8(pfP[2],pfP[3]);
    }

    // ---- row constants (lanes 0..31 of wave 0; same reduce order as before)
    if (tid < 32){
      const float* cs = (const float*)(sm + CONST_OFF);
      float gs=0.f,gq=0.f,gw=0.f,ps=0.f,pq=0.f,pw=0.f;
      #pragma unroll
      for (int w2 = 0; w2 < 4; ++w2){
        float4 sg_ = *(const float4*)(sm + STATS_OFF + tid*144 + (w2*2  )*16);
        float4 sp_ = *(const float4*)(sm + STATS_OFF + tid*144 + (w2*2+1)*16);
        gs+=sg_.x; gq+=sg_.y; gw+=sg_.z;
        ps+=sp_.x; pq+=sp_.y; pw+=sp_.z;
      }
      float mg = gs*(1.f/256.f), vg = fmaxf(gq*(1.f/256.f) - mg*mg, 0.f);
      float rsg = rsqrtf(vg + 1e-5f);
      float mp = ps*(1.f/256.f), vp = fmaxf(pq*(1.f/256.f) - mp*mp, 0.f);
      float rsp = rsqrtf(vp + 1e-5f);
      float sp = rsg*(gw - mg*cs[0]) + cs[1];   // dot(g_ln, wpa)
      float sg = rsp*(pw - mp*cs[2]) + cs[3];   // dot(p_ln, wga)
      float* rc = (float*)(sm + ROWC_OFF) + tid*9;
      rc[0]=mg; rc[1]=rsg; rc[2]=mp; rc[3]=rsp; rc[4]=sg; rc[5]=sp;
    }
    __syncthreads();   // (3) rowc visible

    // ---- phase A: contrib for the OTHER half rows -> exchange buffer
    {
      const int s = 1 - mat;      // g-waves export rows 16..31; p-waves rows 0..15
      #pragma unroll
      for (int reg = 0; reg < 4; ++reg){
        int r = s*16 + q*4 + reg;
        const float* rc = (const float*)(sm + ROWC_OFF) + r*9;
        float mean = rc[mat*2], rs = rc[mat*2+1], srow = rc[4+mat];
        float4 cv;
        #pragma unroll
        for (int t = 0; t < 4; ++t){
          float ln = fmaf((acc[s][t][reg]-mean)*rs, ((const float*)&gamv)[t], ((const float*)&betv)[t]);
          ((float*)&cv)[t] = ln * sigmoid_fast(fmaf(ln, srow, attb));
        }
        int off = mat ? (EXP_OFF + r*1040) : (EXG_OFF + (r-16)*1040);
        *(float4*)(sm + off + colb*4) = cv;
      }
    }
    __syncthreads();   // (4) exchange visible

    // ---- phase B: own half + partner contrib -> out  (order: p + g, as before)
    {
      const int s = mat;          // g-waves store rows 0..15; p-waves rows 16..31
      #pragma unroll
      for (int reg = 0; reg < 4; ++reg){
        int r = s*16 + q*4 + reg;
        const float* rc = (const float*)(sm + ROWC_OFF) + r*9;
        float mean = rc[mat*2], rs = rc[mat*2+1], srow = rc[4+mat];
        int off = mat ? (EXG_OFF + (r-16)*1040) : (EXP_OFF + r*1040);
        float4 pc = *(const float4*)(sm + off + colb*4);
        float4 o;
        #pragma unroll
        for (int t = 0; t < 4; ++t){
          float ln = fmaf((acc[s][t][reg]-mean)*rs, ((const float*)&gamv)[t], ((const float*)&betv)[t]);
          float cown = ln * sigmoid_fast(fmaf(ln, srow, attb));
          ((float*)&o)[t] = mat ? (cown + ((const float*)&pc)[t])      // p + g
                                : (((const float*)&pc)[t] + cown);     // p + g
        }
        *(float4*)(out + (size_t)e*BLD + ((size_t)tile*32 + r)*DDIM + colb) = o;
      }
    }
    __syncthreads();   // (5) next buf staged & exch reads done
    cur ^= 1;
  }
}

extern "C" void kernel_launch(void* const* d_in, const int* in_sizes, int n_in,
                              void* d_out, int out_size, void* d_ws, size_t ws_size,
                              hipStream_t stream) {
  const float* gfeat = (const float*)d_in[0];
  const float* pfeat = (const float*)d_in[1];
  const float* Wg    = (const float*)d_in[2];
  const float* bg    = (const float*)d_in[3];
  const float* gng   = (const float*)d_in[4];
  const float* gnb   = (const float*)d_in[5];
  const float* Wp    = (const float*)d_in[6];
  const float* bp    = (const float*)d_in[7];
  const float* pngm  = (const float*)d_in[8];
  const float* pnb   = (const float*)d_in[9];
  const float* wga   = (const float*)d_in[10];
  const float* bga   = (const float*)d_in[11];
  const float* wpa   = (const float*)d_in[12];
  const float* bpa   = (const float*)d_in[13];

  dim3 grid(256), block(512);
  hipLaunchKernelGGL(kd_kernel, grid, block, 0, stream,
                     gfeat, pfeat, Wg, bg, gng, gnb, Wp, bp, pngm, pnb,
                     wga, bga, wpa, bpa, (float*)d_out);
}

// Round 6
// 451.228 us; speedup vs baseline: 1.2703x; 1.2703x over previous
//
#include <hip/hip_runtime.h>
#include <stdint.h>

typedef __bf16 bf16x8 __attribute__((ext_vector_type(8)));
typedef float  f32x4  __attribute__((ext_vector_type(4)));

#define BLD   16777216   // 4096*16*256
#define DDIM  256
#define NT    4          // 64-row tiles per block (per encoder)

// ---- LDS map (bytes) ----
#define AG_OFF    0        // g-GEMM A (= pfeat tile): 64x256 bf16, XOR-swizzled, 32KB
#define AP_OFF    32768    // p-GEMM A (= gfeat tile): 32KB
#define PARAM_OFF 65536    // [e][8 arrays][256] f32 = 16KB
#define STATS_OFF 81920    // [wave][64 rows] x 9 f32 = 18432B
#define ROWC_OFF  100352   // 64 rows x 9 f32 = 2304B
#define CONST_OFF 102656   // [e][4] f32 = 32B
#define SMEM_BYTES 102688  // 1 block/CU (<= 160KB)

__device__ __forceinline__ float sigmoid_fast(float x){
  float e = __builtin_amdgcn_exp2f(-1.44269504f * x);
  return __builtin_amdgcn_rcpf(1.0f + e);
}

// load 8 consecutive f32, convert to packed bf16x8 (RNE via compiler fptrunc)
__device__ __forceinline__ bf16x8 cvt8(const float* p){
  float4 a = *(const float4*)p;
  float4 b = *(const float4*)(p + 4);
  bf16x8 r;
  r[0]=(__bf16)a.x; r[1]=(__bf16)a.y; r[2]=(__bf16)a.z; r[3]=(__bf16)a.w;
  r[4]=(__bf16)b.x; r[5]=(__bf16)b.y; r[6]=(__bf16)b.z; r[7]=(__bf16)b.w;
  return r;
}

// param array ids: 0 bg, 1 gng, 2 gnb, 3 bp, 4 png, 5 pnb, 6 wga, 7 wpa
__device__ __forceinline__ float ldp(const unsigned char* sm, int e, int arr, int col){
  return ((const float*)(sm + PARAM_OFF))[(e*8 + arr)*256 + col];
}

__global__ __launch_bounds__(512, 2)
void kd_kernel(const float* __restrict__ gfeat, const float* __restrict__ pfeat,
               const float* __restrict__ Wg,  const float* __restrict__ bg,
               const float* __restrict__ gng, const float* __restrict__ gnb,
               const float* __restrict__ Wp,  const float* __restrict__ bp,
               const float* __restrict__ pngm,const float* __restrict__ pnb,
               const float* __restrict__ wga, const float* __restrict__ bga,
               const float* __restrict__ wpa, const float* __restrict__ bpa,
               float* __restrict__ out)
{
  __shared__ __align__(16) unsigned char sm[SMEM_BYTES];
  const int tid  = threadIdx.x;        // 0..511
  const int n    = tid & 15;           // MFMA m/n lane
  const int q    = (tid >> 4) & 3;     // k-quad / row-quad
  const int wv   = tid >> 6;           // wave 0..7: owns cols [32wv, 32wv+32), BOTH mats
  const int q16  = q*16;
  const int xorv = (n & 7) << 4;       // A-LDS swizzle (row&7 == n&7 on frag reads)
  const int colb = wv*32 + n*2;        // lane's first output col (t in {0,1})
  const int tb   = blockIdx.x * NT;    // first 64-row tile of this block

  // ---- stage params (both encoders) into LDS
  {
    const int pe = tid >> 8, pc = tid & 255;
    float* pp = (float*)(sm + PARAM_OFF) + pe*2048;
    pp[0*256+pc] = bg  [pe*256+pc];
    pp[1*256+pc] = gng [pe*256+pc];
    pp[2*256+pc] = gnb [pe*256+pc];
    pp[3*256+pc] = bp  [pe*256+pc];
    pp[4*256+pc] = pngm[pe*256+pc];
    pp[5*256+pc] = pnb [pe*256+pc];
    pp[6*256+pc] = wga [pe*256+pc];
    pp[7*256+pc] = wpa [pe*256+pc];
  }

  // A staging geometry: thread covers row srow, cols {scol + 64c}, fully coalesced
  const int srow = tid >> 3;           // 0..63
  const int scol = (tid & 7) * 8;      // 0..56

  // ---- stage tile tb (round 0). Reference swap: g-GEMM A = pfeat, p-GEMM A = gfeat.
  {
    const float* pg = pfeat + ((size_t)tb*64 + srow)*DDIM;
    const float* pv = gfeat + ((size_t)tb*64 + srow)*DDIM;
    #pragma unroll
    for (int c = 0; c < 4; ++c){
      int col = scol + c*64;
      int off = srow*512 + ((col*2) ^ ((srow & 7) << 4));
      *(bf16x8*)(sm + AG_OFF + off) = cvt8(pg + col);
      *(bf16x8*)(sm + AP_OFF + off) = cvt8(pv + col);
    }
  }
  __syncthreads();

  // ---- dot-fold constants, one encoder per wave (waves 0,1):
  // C0=sum(gng*wpa), C1=sum(gnb*wpa), C2=sum(png*wga), C3=sum(pnb*wga)
  if (tid < 128){
    const int e2 = tid >> 6, l = tid & 63;
    float c0=0.f, c1=0.f, c2=0.f, c3=0.f;
    #pragma unroll
    for (int j = 0; j < 4; ++j){
      int c = l*4 + j;
      float gng_=ldp(sm,e2,1,c), gnb_=ldp(sm,e2,2,c);
      float png_=ldp(sm,e2,4,c), pnb_=ldp(sm,e2,5,c);
      float wga_=ldp(sm,e2,6,c), wpa_=ldp(sm,e2,7,c);
      c0 += gng_*wpa_; c1 += gnb_*wpa_; c2 += png_*wga_; c3 += pnb_*wga_;
    }
    #pragma unroll
    for (int m = 1; m <= 32; m <<= 1){
      c0 += __shfl_xor(c0,m); c1 += __shfl_xor(c1,m);
      c2 += __shfl_xor(c2,m); c3 += __shfl_xor(c3,m);
    }
    if (l == 0){
      float* cp = (float*)(sm + CONST_OFF) + e2*4;
      cp[0]=c0; cp[1]=c1; cp[2]=c2; cp[3]=c3;
    }
  }

  // W fragments for current encoder: both mats, this wave's 32 cols = 128 VGPR
  bf16x8 wfG[8][2], wfP[8][2];
  float biasG[2], gamG[2], betG[2], biasP[2], gamP[2], betP[2], gwk[2], pwk[2];
  float attbG = 0.f, attbP = 0.f;

  for (int rr = 0; rr < 2*NT; ++rr){
    const int e    = rr >> 2;
    const int tile = tb + (rr & 3);

    if ((rr & 3) == 0){
      // ---- load W fragments ONCE per encoder phase (amortized over NT tiles)
      const float* wgE = Wg + (size_t)e*65536;
      const float* wpE = Wp + (size_t)e*65536;
      #pragma unroll
      for (int kk = 0; kk < 8; ++kk){
        #pragma unroll
        for (int t = 0; t < 2; ++t){
          wfG[kk][t] = cvt8(wgE + (size_t)(colb + t)*DDIM + kk*32 + q*8);
          wfP[kk][t] = cvt8(wpE + (size_t)(colb + t)*DDIM + kk*32 + q*8);
        }
      }
      #pragma unroll
      for (int t = 0; t < 2; ++t){
        int col = colb + t;
        biasG[t]=ldp(sm,e,0,col); gamG[t]=ldp(sm,e,1,col); betG[t]=ldp(sm,e,2,col);
        biasP[t]=ldp(sm,e,3,col); gamP[t]=ldp(sm,e,4,col); betP[t]=ldp(sm,e,5,col);
        float wgav=ldp(sm,e,6,col), wpav=ldp(sm,e,7,col);
        gwk[t]=gamG[t]*wpav;   // weight for sp = dot(g_ln, wpa) fold
        pwk[t]=gamP[t]*wgav;   // weight for sg = dot(p_ln, wga) fold
      }
      attbG = bga[e]; attbP = bpa[e];
    }

    // ---- GEMM: acc init = bias; K-loop is pure ds_read + MFMA
    f32x4 accG[4][2], accP[4][2];
    #pragma unroll
    for (int s = 0; s < 4; ++s)
      #pragma unroll
      for (int t = 0; t < 2; ++t){
        accG[s][t] = (f32x4){biasG[t],biasG[t],biasG[t],biasG[t]};
        accP[s][t] = (f32x4){biasP[t],biasP[t],biasP[t],biasP[t]};
      }
    #pragma unroll
    for (int kk = 0; kk < 8; ++kk){
      const int co = (kk*64 + q16) ^ xorv;
      #pragma unroll
      for (int s = 0; s < 4; ++s){
        bf16x8 aG = *(const bf16x8*)(sm + AG_OFF + (s*16 + n)*512 + co);
        bf16x8 aP = *(const bf16x8*)(sm + AP_OFF + (s*16 + n)*512 + co);
        #pragma unroll
        for (int t = 0; t < 2; ++t){
          accG[s][t] = __builtin_amdgcn_mfma_f32_16x16x32_bf16(aG, wfG[kk][t], accG[s][t], 0,0,0);
          accP[s][t] = __builtin_amdgcn_mfma_f32_16x16x32_bf16(aP, wfP[kk][t], accP[s][t], 0,0,0);
        }
      }
    }

    // ---- stats: per row sums (xs, xq, xw) for both mats
    #pragma unroll
    for (int s = 0; s < 4; ++s){
      #pragma unroll
      for (int reg = 0; reg < 4; ++reg){
        float gs=0.f,gq=0.f,gw=0.f,ps=0.f,pq=0.f,pw=0.f;
        #pragma unroll
        for (int t = 0; t < 2; ++t){
          float xg = accG[s][t][reg], xp = accP[s][t][reg];
          gs += xg; gq = fmaf(xg,xg,gq); gw = fmaf(xg,gwk[t],gw);
          ps += xp; pq = fmaf(xp,xp,pq); pw = fmaf(xp,pwk[t],pw);
        }
        #pragma unroll
        for (int m = 1; m <= 8; m <<= 1){
          gs += __shfl_xor(gs,m); gq += __shfl_xor(gq,m); gw += __shfl_xor(gw,m);
          ps += __shfl_xor(ps,m); pq += __shfl_xor(pq,m); pw += __shfl_xor(pw,m);
        }
        if (n == 0){
          int r = s*16 + q*4 + reg;                  // 0..63
          float* st = (float*)(sm + STATS_OFF) + (wv*64 + r)*9;  // stride 9: conflict-free
          st[0]=gs; st[1]=gq; st[2]=gw; st[3]=ps; st[4]=pq; st[5]=pw;
        }
      }
    }
    __syncthreads();   // stats visible; all A reads of this round done

    // ---- row constants (wave 0: one row per lane)
    if (tid < 64){
      const float* cs = (const float*)(sm + CONST_OFF) + e*4;
      float gs=0.f,gq=0.f,gw=0.f,ps=0.f,pq=0.f,pw=0.f;
      #pragma unroll
      for (int w2 = 0; w2 < 8; ++w2){
        const float* st = (const float*)(sm + STATS_OFF) + (w2*64 + tid)*9;
        gs+=st[0]; gq+=st[1]; gw+=st[2]; ps+=st[3]; pq+=st[4]; pw+=st[5];
      }
      float mg = gs*(1.f/256.f), vg = fmaxf(gq*(1.f/256.f) - mg*mg, 0.f);
      float rsg = rsqrtf(vg + 1e-5f);
      float mp = ps*(1.f/256.f), vp = fmaxf(pq*(1.f/256.f) - mp*mp, 0.f);
      float rsp = rsqrtf(vp + 1e-5f);
      float spv = rsg*(gw - mg*cs[0]) + cs[1];   // dot(g_ln, wpa)
      float sgv = rsp*(pw - mp*cs[2]) + cs[3];   // dot(p_ln, wga)
      float* rc = (float*)(sm + ROWC_OFF) + tid*9;
      rc[0]=mg; rc[1]=rsg; rc[2]=mp; rc[3]=rsp; rc[4]=sgv; rc[5]=spv;
    }
    __syncthreads();   // rowc visible

    // ---- epilogue + store (acc dies here)
    #pragma unroll
    for (int s = 0; s < 4; ++s){
      #pragma unroll
      for (int reg = 0; reg < 4; ++reg){
        int r = s*16 + q*4 + reg;
        const float* rc = (const float*)(sm + ROWC_OFF) + r*9;
        float mg=rc[0], rsg=rc[1], mp=rc[2], rsp=rc[3], sgv=rc[4], spv=rc[5];
        float ov[2];
        #pragma unroll
        for (int t = 0; t < 2; ++t){
          float g_ln = fmaf((accG[s][t][reg]-mg)*rsg, gamG[t], betG[t]);
          float p_ln = fmaf((accP[s][t][reg]-mp)*rsp, gamP[t], betP[t]);
          float ga = sigmoid_fast(fmaf(g_ln, sgv, attbG));  // geno_att
          float pa = sigmoid_fast(fmaf(p_ln, spv, attbP));  // path_att
          ov[t] = p_ln*pa + g_ln*ga;
        }
        float2 o2; o2.x = ov[0]; o2.y = ov[1];
        *(float2*)(out + (size_t)e*BLD + ((size_t)tile*64 + r)*DDIM + colb) = o2;
      }
    }

    // ---- stage next round's A (acc dead -> no reg-pressure collision with wf)
    if (rr + 1 < 2*NT){
      const int ti = tb + ((rr+1) & 3);
      const float* pg = pfeat + ((size_t)ti*64 + srow)*DDIM;
      const float* pv = gfeat + ((size_t)ti*64 + srow)*DDIM;
      #pragma unroll
      for (int c = 0; c < 4; ++c){
        int col = scol + c*64;
        int off = srow*512 + ((col*2) ^ ((srow & 7) << 4));
        *(bf16x8*)(sm + AG_OFF + off) = cvt8(pg + col);
        *(bf16x8*)(sm + AP_OFF + off) = cvt8(pv + col);
      }
      __syncthreads();   // A(next) staged before next K-loop
    }
  }
}

extern "C" void kernel_launch(void* const* d_in, const int* in_sizes, int n_in,
                              void* d_out, int out_size, void* d_ws, size_t ws_size,
                              hipStream_t stream) {
  const float* gfeat = (const float*)d_in[0];
  const float* pfeat = (const float*)d_in[1];
  const float* Wg    = (const float*)d_in[2];
  const float* bg    = (const float*)d_in[3];
  const float* gng   = (const float*)d_in[4];
  const float* gnb   = (const float*)d_in[5];
  const float* Wp    = (const float*)d_in[6];
  const float* bp    = (const float*)d_in[7];
  const float* pngm  = (const float*)d_in[8];
  const float* pnb   = (const float*)d_in[9];
  const float* wga   = (const float*)d_in[10];
  const float* bga   = (const float*)d_in[11];
  const float* wpa   = (const float*)d_in[12];
  const float* bpa   = (const float*)d_in[13];

  dim3 grid(256), block(512);
  hipLaunchKernelGGL(kd_kernel, grid, block, 0, stream,
                     gfeat, pfeat, Wg, bg, gng, gnb, Wp, bp, pngm, pnb,
                     wga, bga, wpa, bpa, (float*)d_out);
}